// Round 4
// baseline (29.047 us; speedup 1.0000x reference)
//
#include <hip/hip_runtime.h>
#include <math.h>

#define BLOCK 256
#define LOCS  128         // locations per block; 4-lane group handles loc i and i+64
#define MAXG  64
#define NSUM  5           // [cls, box_num, w_sum, ctr_sum, npos]

__device__ __forceinline__ void do_loc(
    int i, int N, int b, int sub, bool uni,
    const float4 (*sg)[4], const float* sgf,
    const float* __restrict__ loc, const float* __restrict__ clsp,
    const float* __restrict__ boxp, const float* __restrict__ ctrp,
    const float* __restrict__ spt, const float* __restrict__ soi,
    int G, int C,
    float& cls, float& box, float& w, float& ctr, float& npv)
{
    if (i >= N) return;

    const float x = loc[(size_t)i * 3 + 0];
    const float y = loc[(size_t)i * 3 + 1];
    const float z = loc[(size_t)i * 3 + 2];
    const float2 sh = *(const float2*)(soi + (size_t)i * 2);
    const float lo = sh.x, hi = sh.y;
    const float s = uni ? 0.f : spt[i];   // only needed on fallback path

    float best = 1e9f;   // INF, exactly representable in fp32
    int   bid  = 0;
    #pragma unroll 2
    for (int g = sub; g < G; g += 4) {
        const float4 q0 = sg[g][0];
        const float4 q1 = sg[g][1];
        const float l = x - q0.x, t  = y - q0.y, f = z - q0.z;
        const float r = q0.w - x, bb = q1.x - y, a = q1.y - z;
        const float mx = fmaxf(fmaxf(fmaxf(l, t), fmaxf(f, r)), fmaxf(bb, a));
        bool ok = (mx >= lo) & (mx <= hi);
        if (uni) {
            const float4 q2 = sg[g][2];
            const float4 q3 = sg[g][3];
            ok = ok & (x > q2.x) & (y > q2.y) & (z > q2.z)
                    & (x < q3.x) & (y < q3.y) & (z < q3.z);
        } else {
            const float cx = (q0.x + q0.w) * 0.5f;
            const float cy = (q0.y + q1.x) * 0.5f;
            const float cz = (q0.z + q1.y) * 0.5f;
            ok = ok & (x > fmaxf(cx - s, q0.x)) & (y > fmaxf(cy - s, q0.y))
                    & (z > fmaxf(cz - s, q0.z)) & (x < fminf(cx + s, q0.w))
                    & (y < fminf(cy + s, q1.x)) & (z < fminf(cz + s, q1.y));
        }
        const float l2a = ok ? q1.z : 1e9f;
        if (l2a < best) { best = l2a; bid = g; }  // strict <: first-min in own subset
    }
    // 4-lane argmin reduce, ties -> smallest g (matches jnp.argmin)
    #pragma unroll
    for (int off = 1; off < 4; off <<= 1) {
        const float ob   = __shfl_xor(best, off, 4);
        const int   obid = __shfl_xor(bid,  off, 4);
        if (ob < best || (ob == best && obid < bid)) { best = ob; bid = obid; }
    }
    const int label = (best < 1e9f) ? __float_as_int(sgf[bid * 16 + 7]) : 0;

    // focal loss: 4-lane group covers all C classes; fast path C==8 (2/lane)
    if (C == 8) {
        const float2 v2 = *(const float2*)(clsp + ((size_t)b * N + i) * 8 + sub * 2);
        const float vv[2] = {v2.x, v2.y};
        #pragma unroll
        for (int k = 0; k < 2; ++k) {
            const int   c = sub * 2 + k;
            const float v = vv[k];
            const float e  = __expf(-fabsf(v));
            const float sp = __logf(1.0f + e);          // softplus(-|v|)
            const float lsm = fminf(v, 0.f) - sp;       // log sigmoid(v)
            const float lsn = -fmaxf(v, 0.f) - sp;      // log sigmoid(-v)
            const float inv = 1.0f / (1.0f + e);
            const float p   = (v >= 0.f) ? inv : e * inv;
            cls += (label == c + 1) ? -0.25f * (1.f - p) * (1.f - p) * lsm
                                    : -0.75f * p * p * lsn;
        }
    } else {
        for (int c = sub; c < C; c += 4) {
            const float v = clsp[((size_t)b * N + i) * (size_t)C + c];
            const float e  = __expf(-fabsf(v));
            const float sp = __logf(1.0f + e);
            const float lsm = fminf(v, 0.f) - sp;
            const float lsn = -fmaxf(v, 0.f) - sp;
            const float inv = 1.0f / (1.0f + e);
            const float p   = (v >= 0.f) ? inv : e * inv;
            cls += (label == c + 1) ? -0.25f * (1.f - p) * (1.f - p) * lsm
                                    : -0.75f * p * p * lsn;
        }
    }

    if (label > 0 && sub == 0) {
        const float4 q0 = sg[bid][0];
        const float4 q1 = sg[bid][1];
        const float l = x - q0.x, t  = y - q0.y, f = z - q0.z;
        const float r = q0.w - x, bb = q1.x - y, a = q1.y - z;

        const float rx = fminf(l, r)  / fmaxf(l, r);
        const float ry = fminf(t, bb) / fmaxf(t, bb);
        const float rz = fminf(f, a)  / fmaxf(f, a);
        float c2 = rx * ry * rz;
        c2 = fminf(fmaxf(c2, 1e-8f), 1.0f);
        const float ct = sqrtf(c2);

        const float* bp = boxp + ((size_t)b * N + i) * 6;
        const float2 ba  = *(const float2*)(bp);
        const float2 bbv = *(const float2*)(bp + 2);
        const float2 bc  = *(const float2*)(bp + 4);
        const float p0 = ba.x,  p1 = ba.y,  p2 = bbv.x;
        const float p3 = bbv.y, p4 = bc.x,  p5 = bc.y;
        const float pv = (p0 + p3) * (p1 + p4) * (p2 + p5);
        const float tv = (l + r) * (t + bb) * (f + a);
        const float m0 = fminf(p0, l), m1 = fminf(p1, t),  m2 = fminf(p2, f);
        const float m3 = fminf(p3, r), m4 = fminf(p4, bb), m5 = fminf(p5, a);
        const float inter = (m0 + m3) * (m1 + m4) * (m2 + m5);
        const float uni2  = pv + tv - inter;
        const float iou   = (inter + 1.0f) / (uni2 + 1.0f);
        const float il    = -__logf(fmaxf(iou, 1e-6f));
        box += il * ct;
        w   += ct;
        const float cv = ctrp[(size_t)b * N + i];
        ctr += fmaxf(cv, 0.f) - cv * ct + __logf(1.f + __expf(-fabsf(cv)));
        npv += 1.f;
    }
}

__global__ __launch_bounds__(BLOCK) void fcos_main(
    const float* __restrict__ loc,    // N x 3
    const float* __restrict__ clsp,   // B x N x C
    const float* __restrict__ boxp,   // B x N x 6
    const float* __restrict__ ctrp,   // B x N
    const float* __restrict__ bboxes, // B x G x 6
    const int*   __restrict__ glab,   // B x G
    const float* __restrict__ spt,    // N
    const float* __restrict__ soi,    // N x 2
    int N, int G, int C, int nblk,
    double* __restrict__ part)        // NSUM x nblk partials (SoA)
{
    // per-g struct: [0]=b0,b1,b2,b3  [1]=b4,b5,area,label_bits
    //               [2]=cminx,cminy,cminz,-  [3]=cmaxx,cmaxy,cmaxz,-
    __shared__ float4 sg[MAXG][4];
    __shared__ double sred[(BLOCK / 64) * NSUM];
    __shared__ int sUni;

    const int b    = blockIdx.y;
    const int blk0 = blockIdx.x * LOCS;

    if (threadIdx.x == 0) {
        const int last = min(blk0 + LOCS - 1, N - 1);
        sUni = (spt[blk0] == spt[last]) ? 1 : 0;   // stride uniform over block?
    }
    if (threadIdx.x < G) {
        const int g = threadIdx.x;
        const float* p = bboxes + ((size_t)b * G + g) * 6;
        const float b0 = p[0], b1 = p[1], b2 = p[2];
        const float b3 = p[3], b4 = p[4], b5 = p[5];
        const float s  = spt[blk0];                // block's stride (valid if sUni)
        const float cx = (b0 + b3) * 0.5f, cy = (b1 + b4) * 0.5f, cz = (b2 + b5) * 0.5f;
        const float area = (b3 - b0) * (b4 - b1) * (b5 - b2);  // jnp.prod order
        const int   lab  = glab[b * G + g];
        sg[g][0] = make_float4(b0, b1, b2, b3);
        sg[g][1] = make_float4(b4, b5, area, __int_as_float(lab));
        sg[g][2] = make_float4(fmaxf(cx - s, b0), fmaxf(cy - s, b1), fmaxf(cz - s, b2), 0.f);
        sg[g][3] = make_float4(fminf(cx + s, b3), fminf(cy + s, b4), fminf(cz + s, b5), 0.f);
    }
    __syncthreads();

    const int sub = threadIdx.x & 3;          // lane within 4-lane group
    const int i0  = blk0 + (threadIdx.x >> 2);
    const bool uni = (sUni != 0);
    const float* sgf = (const float*)&sg[0][0];

    float cls = 0.f, box = 0.f, w = 0.f, ctr = 0.f, npv = 0.f;

    do_loc(i0,      N, b, sub, uni, sg, sgf, loc, clsp, boxp, ctrp, spt, soi, G, C,
           cls, box, w, ctr, npv);
    do_loc(i0 + 64, N, b, sub, uni, sg, sgf, loc, clsp, boxp, ctrp, spt, soi, G, C,
           cls, box, w, ctr, npv);

    // wave-64 reduce in fp32 (block partial ~O(100): fp32 error ~1e-5, threshold 1.5)
    #pragma unroll
    for (int off = 32; off > 0; off >>= 1) {
        cls += __shfl_down(cls, off, 64);
        box += __shfl_down(box, off, 64);
        w   += __shfl_down(w,   off, 64);
        ctr += __shfl_down(ctr, off, 64);
        npv += __shfl_down(npv, off, 64);
    }
    const int wv = threadIdx.x >> 6;
    if ((threadIdx.x & 63) == 0) {
        sred[wv * NSUM + 0] = (double)cls;
        sred[wv * NSUM + 1] = (double)box;
        sred[wv * NSUM + 2] = (double)w;
        sred[wv * NSUM + 3] = (double)ctr;
        sred[wv * NSUM + 4] = (double)npv;
    }
    __syncthreads();
    if (threadIdx.x < NSUM) {
        double v = 0.0;
        #pragma unroll
        for (int k = 0; k < BLOCK / 64; ++k) v += sred[k * NSUM + threadIdx.x];
        const int blk = blockIdx.y * gridDim.x + blockIdx.x;
        part[(size_t)threadIdx.x * nblk + blk] = v;   // SoA: coalesced for final
    }
}

__global__ __launch_bounds__(320) void fcos_final(
    const double* __restrict__ part, int nblk,
    float* __restrict__ out, int B)
{
    __shared__ double shm[NSUM];
    const int wv = threadIdx.x >> 6;   // 0..4 — one wave per accumulator
    const int ln = threadIdx.x & 63;
    double a = 0.0;
    const double* p = part + (size_t)wv * nblk;
    for (int k = ln; k < nblk; k += 64) a += p[k];
    #pragma unroll
    for (int off = 32; off > 0; off >>= 1) a += __shfl_down(a, off, 64);
    if (ln == 0) shm[wv] = a;
    __syncthreads();
    if (threadIdx.x == 0) {
        const double np = shm[4];
        out[0] = (float)(shm[0] / (np + (double)B));
        out[1] = (float)(shm[1] / fmax(shm[2], 1e-8));
        out[2] = (float)(shm[3] / fmax(np, 1.0));
    }
}

extern "C" void kernel_launch(void* const* d_in, const int* in_sizes, int n_in,
                              void* d_out, int out_size, void* d_ws, size_t ws_size,
                              hipStream_t stream) {
    const float* loc  = (const float*)d_in[0];
    const float* clsp = (const float*)d_in[1];
    const float* boxp = (const float*)d_in[2];
    const float* ctrp = (const float*)d_in[3];
    const float* bbox = (const float*)d_in[4];
    const int*   glab = (const int*)d_in[5];
    // d_in[6] = gt_centers (unused by the reference computation)
    const float* spt  = (const float*)d_in[7];
    const float* soi  = (const float*)d_in[8];

    const int N = in_sizes[7];                 // strides_pt: (N,)
    const int B = in_sizes[3] / N;             // center_pred: (B,N)
    const int G = in_sizes[5] / B;             // gt_labels: (B,G)
    const int C = in_sizes[1] / in_sizes[3];   // cls_pred: (B,N,C)

    const int gx   = (N + LOCS - 1) / LOCS;
    const int nblk = gx * B;
    double* part = (double*)d_ws;              // NSUM * nblk doubles, SoA

    dim3 grid(gx, B);
    fcos_main<<<grid, BLOCK, 0, stream>>>(loc, clsp, boxp, ctrp, bbox, glab, spt, soi,
                                          N, G, C, nblk, part);
    fcos_final<<<1, 320, 0, stream>>>(part, nblk, (float*)d_out, B);
}

// Round 5
// 21.709 us; speedup vs baseline: 1.3380x; 1.3380x over previous
//
#include <hip/hip_runtime.h>
#include <math.h>

#define BLOCK 256   // one location per thread
#define MAXG  64
#define NSUM  5     // [cls, box_num, w_sum, ctr_sum, npos]

__global__ __launch_bounds__(BLOCK) void fcos_main(
    const float* __restrict__ loc,    // N x 3
    const float* __restrict__ clsp,   // B x N x C
    const float* __restrict__ boxp,   // B x N x 6
    const float* __restrict__ ctrp,   // B x N
    const float* __restrict__ bboxes, // B x G x 6
    const int*   __restrict__ glab,   // B x G
    const float* __restrict__ spt,    // N
    const float* __restrict__ soi,    // N x 2
    int N, int G, int C, int nblk,
    double* __restrict__ part)        // NSUM x nblk partials (SoA)
{
    // fast-path test data (valid when block has uniform stride):
    //   sA[g] = (Xlo, Xhi, Ylo, Yhi)   inside-box  (is_in ∧ max_t<=hi)
    //   sB[g] = (Zlo, Zhi, area, label_bits)
    //   sC[g] = (Ax, Bx, Ay, By)       fail-box    (max_t < lo), empty -> never true
    //   sD[g] = (Az, Bz, -, -)
    // original boxes for slow path + epilogue:
    //   sO[g][0] = (b0,b1,b2,b3)  sO[g][1] = (b4,b5,area,label_bits)
    __shared__ float4 sA[MAXG], sB[MAXG], sC[MAXG], sD[MAXG];
    __shared__ float4 sO[MAXG][2];
    __shared__ double sred[(BLOCK / 64) * NSUM];
    __shared__ int sMode;  // 0 = mixed-stride slow, 1 = level-0 fast, 2 = level>=1 fast

    const int b    = blockIdx.y;
    const int blk0 = blockIdx.x * BLOCK;
    const int i    = blk0 + threadIdx.x;

    if (threadIdx.x == 0) {
        const int last = min(blk0 + BLOCK - 1, N - 1);
        const bool uni = (spt[blk0] == spt[last]);
        sMode = uni ? ((soi[(size_t)blk0 * 2] < 0.f) ? 1 : 2) : 0;
    }
    if (threadIdx.x < G) {
        const int g = threadIdx.x;
        const float* p = bboxes + ((size_t)b * G + g) * 6;
        const float b0 = p[0], b1 = p[1], b2 = p[2];
        const float b3 = p[3], b4 = p[4], b5 = p[5];
        const float area = (b3 - b0) * (b4 - b1) * (b5 - b2);  // jnp.prod order
        const float labf = __int_as_float(glab[b * G + g]);
        sO[g][0] = make_float4(b0, b1, b2, b3);
        sO[g][1] = make_float4(b4, b5, area, labf);

        const float s  = spt[blk0];
        const float lo = soi[(size_t)blk0 * 2 + 0];
        const float hi = soi[(size_t)blk0 * 2 + 1];
        const float cx = (b0 + b3) * 0.5f, cy = (b1 + b4) * 0.5f, cz = (b2 + b5) * 0.5f;
        // inside-box: strict x>Xlo & x<Xhi (merges is_in strict with max_t<=hi)
        sA[g] = make_float4(fmaxf(fmaxf(cx - s, b0), b3 - hi),
                            fminf(fminf(cx + s, b3), b0 + hi),
                            fmaxf(fmaxf(cy - s, b1), b4 - hi),
                            fminf(fminf(cy + s, b4), b1 + hi));
        sB[g] = make_float4(fmaxf(fmaxf(cz - s, b2), b5 - hi),
                            fminf(fminf(cz + s, b5), b2 + hi),
                            area, labf);
        // fail-box: max_t < lo  <=>  all dims strictly inside (b3-lo, b0+lo)
        sC[g] = make_float4(b3 - lo, b0 + lo, b4 - lo, b1 + lo);
        sD[g] = make_float4(b5 - lo, b2 + lo, 0.f, 0.f);
    }
    __syncthreads();

    float cls = 0.f, box = 0.f, w = 0.f, ctr = 0.f, npv = 0.f;

    if (i < N) {
        const float x = loc[(size_t)i * 3 + 0];
        const float y = loc[(size_t)i * 3 + 1];
        const float z = loc[(size_t)i * 3 + 2];
        const int mode = sMode;

        float best = 1e9f;   // INF, exactly representable in fp32
        int   bid  = 0;

        if (mode == 1) {
            // level 0 (lo = -1): fail-box provably empty -> 2 LDS reads/GT
            #pragma unroll 4
            for (int g = 0; g < G; ++g) {
                const float4 qa = sA[g];
                const float4 qb = sB[g];
                const float m = fminf(fminf(fminf(x - qa.x, qa.y - x),
                                            fminf(y - qa.z, qa.w - y)),
                                      fminf(z - qb.x, qb.y - z));
                const float l2a = (m > 0.f) ? qb.z : 1e9f;
                if (l2a < best) { best = l2a; bid = g; }  // strict <: first-min
            }
        } else if (mode == 2) {
            #pragma unroll 2
            for (int g = 0; g < G; ++g) {
                const float4 qa = sA[g];
                const float4 qb = sB[g];
                const float4 qc = sC[g];
                const float4 qd = sD[g];
                const float m  = fminf(fminf(fminf(x - qa.x, qa.y - x),
                                             fminf(y - qa.z, qa.w - y)),
                                       fminf(z - qb.x, qb.y - z));
                const float mf = fminf(fminf(fminf(x - qc.x, qc.y - x),
                                             fminf(y - qc.z, qc.w - y)),
                                       fminf(z - qd.x, qd.y - z));
                const bool ok = (m > 0.f) & !(mf > 0.f);
                const float l2a = ok ? qb.z : 1e9f;
                if (l2a < best) { best = l2a; bid = g; }
            }
        } else {
            // mixed-stride block (rare): exact per-lane reference math
            const float s  = spt[i];
            const float2 lh = *(const float2*)(soi + (size_t)i * 2);
            const float lo = lh.x, hi = lh.y;
            for (int g = 0; g < G; ++g) {
                const float4 o0 = sO[g][0];
                const float4 o1 = sO[g][1];
                const float l = x - o0.x, t  = y - o0.y, f = z - o0.z;
                const float r = o0.w - x, bb = o1.x - y, a = o1.y - z;
                const float mx = fmaxf(fmaxf(fmaxf(l, t), fmaxf(f, r)), fmaxf(bb, a));
                bool ok = (mx >= lo) & (mx <= hi);
                const float cx = (o0.x + o0.w) * 0.5f;
                const float cy = (o0.y + o1.x) * 0.5f;
                const float cz = (o0.z + o1.y) * 0.5f;
                ok = ok & (x > fmaxf(cx - s, o0.x)) & (y > fmaxf(cy - s, o0.y))
                        & (z > fmaxf(cz - s, o0.z)) & (x < fminf(cx + s, o0.w))
                        & (y < fminf(cy + s, o1.x)) & (z < fminf(cz + s, o1.y));
                const float l2a = ok ? o1.z : 1e9f;
                if (l2a < best) { best = l2a; bid = g; }
            }
        }

        int label = 0;
        float4 o0, o1;
        if (best < 1e9f) {
            o0 = sO[bid][0];
            o1 = sO[bid][1];
            label = __float_as_int(o1.w);
        }

        // focal loss over all C classes (every location contributes)
        if (C == 8) {
            const float4 v0 = *(const float4*)(clsp + ((size_t)b * N + i) * 8);
            const float4 v1 = *(const float4*)(clsp + ((size_t)b * N + i) * 8 + 4);
            const float vv[8] = {v0.x, v0.y, v0.z, v0.w, v1.x, v1.y, v1.z, v1.w};
            #pragma unroll
            for (int c = 0; c < 8; ++c) {
                const float v = vv[c];
                const float e   = __expf(-fabsf(v));
                const float sp  = __logf(1.0f + e);          // softplus(-|v|)
                const float lsm = fminf(v, 0.f) - sp;        // log sigmoid(v)
                const float lsn = -fmaxf(v, 0.f) - sp;       // log sigmoid(-v)
                const float inv = 1.0f / (1.0f + e);
                const float p   = (v >= 0.f) ? inv : e * inv;
                cls += (label == c + 1) ? -0.25f * (1.f - p) * (1.f - p) * lsm
                                        : -0.75f * p * p * lsn;
            }
        } else {
            for (int c = 0; c < C; ++c) {
                const float v = clsp[((size_t)b * N + i) * (size_t)C + c];
                const float e   = __expf(-fabsf(v));
                const float sp  = __logf(1.0f + e);
                const float lsm = fminf(v, 0.f) - sp;
                const float lsn = -fmaxf(v, 0.f) - sp;
                const float inv = 1.0f / (1.0f + e);
                const float p   = (v >= 0.f) ? inv : e * inv;
                cls += (label == c + 1) ? -0.25f * (1.f - p) * (1.f - p) * lsm
                                        : -0.75f * p * p * lsn;
            }
        }

        if (label > 0) {
            const float l = x - o0.x, t  = y - o0.y, f = z - o0.z;
            const float r = o0.w - x, bb = o1.x - y, a = o1.y - z;

            const float rx = fminf(l, r)  / fmaxf(l, r);
            const float ry = fminf(t, bb) / fmaxf(t, bb);
            const float rz = fminf(f, a)  / fmaxf(f, a);
            float c2 = rx * ry * rz;
            c2 = fminf(fmaxf(c2, 1e-8f), 1.0f);
            const float ct = sqrtf(c2);

            const float* bp = boxp + ((size_t)b * N + i) * 6;
            const float2 ba  = *(const float2*)(bp);
            const float2 bbv = *(const float2*)(bp + 2);
            const float2 bc  = *(const float2*)(bp + 4);
            const float p0 = ba.x,  p1 = ba.y,  p2 = bbv.x;
            const float p3 = bbv.y, p4 = bc.x,  p5 = bc.y;
            const float pv = (p0 + p3) * (p1 + p4) * (p2 + p5);
            const float tv = (l + r) * (t + bb) * (f + a);
            const float m0 = fminf(p0, l), m1 = fminf(p1, t),  m2 = fminf(p2, f);
            const float m3 = fminf(p3, r), m4 = fminf(p4, bb), m5 = fminf(p5, a);
            const float inter = (m0 + m3) * (m1 + m4) * (m2 + m5);
            const float uni2  = pv + tv - inter;
            const float iou   = (inter + 1.0f) / (uni2 + 1.0f);
            const float il    = -__logf(fmaxf(iou, 1e-6f));
            box = il * ct;
            w   = ct;
            const float cv = ctrp[(size_t)b * N + i];
            ctr = fmaxf(cv, 0.f) - cv * ct + __logf(1.f + __expf(-fabsf(cv)));
            npv = 1.f;
        }
    }

    // wave-64 reduce in fp32 (block partial ~O(100): fp32 error ~1e-5, threshold 1.5)
    #pragma unroll
    for (int off = 32; off > 0; off >>= 1) {
        cls += __shfl_down(cls, off, 64);
        box += __shfl_down(box, off, 64);
        w   += __shfl_down(w,   off, 64);
        ctr += __shfl_down(ctr, off, 64);
        npv += __shfl_down(npv, off, 64);
    }
    const int wv = threadIdx.x >> 6;
    if ((threadIdx.x & 63) == 0) {
        sred[wv * NSUM + 0] = (double)cls;
        sred[wv * NSUM + 1] = (double)box;
        sred[wv * NSUM + 2] = (double)w;
        sred[wv * NSUM + 3] = (double)ctr;
        sred[wv * NSUM + 4] = (double)npv;
    }
    __syncthreads();
    if (threadIdx.x < NSUM) {
        double v = 0.0;
        #pragma unroll
        for (int k = 0; k < BLOCK / 64; ++k) v += sred[k * NSUM + threadIdx.x];
        const int blk = blockIdx.y * gridDim.x + blockIdx.x;
        part[(size_t)threadIdx.x * nblk + blk] = v;   // SoA: coalesced for final
    }
}

__global__ __launch_bounds__(320) void fcos_final(
    const double* __restrict__ part, int nblk,
    float* __restrict__ out, int B)
{
    __shared__ double shm[NSUM];
    const int wv = threadIdx.x >> 6;   // 0..4 — one wave per accumulator
    const int ln = threadIdx.x & 63;
    double a = 0.0;
    const double* p = part + (size_t)wv * nblk;
    for (int k = ln; k < nblk; k += 64) a += p[k];
    #pragma unroll
    for (int off = 32; off > 0; off >>= 1) a += __shfl_down(a, off, 64);
    if (ln == 0) shm[wv] = a;
    __syncthreads();
    if (threadIdx.x == 0) {
        const double np = shm[4];
        out[0] = (float)(shm[0] / (np + (double)B));
        out[1] = (float)(shm[1] / fmax(shm[2], 1e-8));
        out[2] = (float)(shm[3] / fmax(np, 1.0));
    }
}

extern "C" void kernel_launch(void* const* d_in, const int* in_sizes, int n_in,
                              void* d_out, int out_size, void* d_ws, size_t ws_size,
                              hipStream_t stream) {
    const float* loc  = (const float*)d_in[0];
    const float* clsp = (const float*)d_in[1];
    const float* boxp = (const float*)d_in[2];
    const float* ctrp = (const float*)d_in[3];
    const float* bbox = (const float*)d_in[4];
    const int*   glab = (const int*)d_in[5];
    // d_in[6] = gt_centers (unused by the reference computation)
    const float* spt  = (const float*)d_in[7];
    const float* soi  = (const float*)d_in[8];

    const int N = in_sizes[7];                 // strides_pt: (N,)
    const int B = in_sizes[3] / N;             // center_pred: (B,N)
    const int G = in_sizes[5] / B;             // gt_labels: (B,G)
    const int C = in_sizes[1] / in_sizes[3];   // cls_pred: (B,N,C)

    const int gx   = (N + BLOCK - 1) / BLOCK;
    const int nblk = gx * B;
    double* part = (double*)d_ws;              // NSUM * nblk doubles, SoA

    dim3 grid(gx, B);
    fcos_main<<<grid, BLOCK, 0, stream>>>(loc, clsp, boxp, ctrp, bbox, glab, spt, soi,
                                          N, G, C, nblk, part);
    fcos_final<<<1, 320, 0, stream>>>(part, nblk, (float*)d_out, B);
}